// Round 9
// baseline (639.028 us; speedup 1.0000x reference)
//
#include <hip/hip_runtime.h>
#include <cmath>

#define BB 4
#define SS 256
#define ZDIM 128
#define GCH 256
#define NBLKS 8
#define NPIX 65536   // 256*256
#define U1C 128      // GC/2

__device__ __forceinline__ float lrelu(float x){ return x >= 0.f ? x : 0.2f*x; }

// grid barrier: 256 co-resident blocks, monotone counter (round-4-proven atomics)
__device__ __forceinline__ void gridbar(int* bar, int target){
  __syncthreads();
  if(threadIdx.x == 0){
    __hip_atomic_fetch_add(bar, 1, __ATOMIC_RELEASE, __HIP_MEMORY_SCOPE_AGENT);
    while(__hip_atomic_load(bar, __ATOMIC_ACQUIRE, __HIP_MEMORY_SCOPE_AGENT) < target)
      __builtin_amdgcn_s_sleep(2);
  }
  __syncthreads();
}

// ---- prep: tiled transpose of A (blocks 0..255), then wT / w2t repack ----
__global__ __launch_bounds__(256) void k_prep(const float* __restrict__ A,
        const float* __restrict__ w1, const float* __restrict__ w2,
        float* __restrict__ At, float* __restrict__ wT, float* __restrict__ w2t){
  int bid = blockIdx.x;
  if(bid < 256){
    __shared__ float t[32][33];
    int b = bid >> 6;
    int bx = (bid & 7)*32, by = ((bid >> 3) & 7)*32;
    int lx = threadIdx.x & 31, ly4 = (threadIdx.x >> 5)*4;
    #pragma unroll
    for(int r=0;r<4;r++)
      t[ly4+r][lx] = A[(b<<16) + ((by+ly4+r)<<8) + bx + lx];
    __syncthreads();
    #pragma unroll
    for(int r=0;r<4;r++)
      At[(b<<16) + ((bx+ly4+r)<<8) + by + lx] = t[lx][ly4+r];
  } else {
    int idx = (bid-256)*256 + threadIdx.x;
    if(idx < 294912){
      int o = idx & 127; int r = idx >> 7; int c = r & 255; int k = r >> 8;
      wT[idx] = w1[(o*GCH + c)*9 + k];
    } else if(idx < 294912 + 3456){
      int t2 = idx - 294912;
      int cc = t2 & 7;
      int oc = (t2 >> 3) % 3;
      int sg = (t2 / 24) & 3;
      int g  = (t2 / 96) & 3;
      int k  = t2 / 384;
      w2t[t2] = w2[oc*1152 + (g*32 + sg*8 + cc)*9 + k];
    }
  }
}

// ---- mega: pool + x0 + 8x(gemm -> s1 -> s2+apply), 256 blocks x 512 thr ----
__global__ __launch_bounds__(512) void k_mega(
    const float* __restrict__ img, const int* __restrict__ seg,
    float* __restrict__ segsum, float* __restrict__ counts,
    const float* __restrict__ z, const float* __restrict__ pw,
    const float* __restrict__ pb, const float* __restrict__ At,
    const float* __restrict__ bw_all, const float* __restrict__ bb_all,
    const float* __restrict__ a1w_all, const float* __restrict__ a1b_all,
    const float* __restrict__ a2w_all, const float* __restrict__ a2b_all,
    float* __restrict__ xp, float* __restrict__ h2,
    float* __restrict__ m, float* __restrict__ s1g, int* __restrict__ bar,
    float sProj, float sc1, float sc2){
  int bid = blockIdx.x;
  int tid = threadIdx.x;
  int lane = tid & 63, wv = tid >> 6;
  __shared__ float ls[1024];
  __shared__ float wl[4][256];
  __shared__ float h1l[4][260];
  __shared__ float red[4][4];
  __shared__ float gbl[8];
  int bt = 0;

  // ---- phase P: segment pooling (1024 px per block) ----
  {
    for(int j=tid;j<1024;j+=512) ls[j]=0.f;
    __syncthreads();
    int b = bid >> 6;
    int base = bid*1024;
    #pragma unroll
    for(int it2=0; it2<2; it2++){
      int idx = base + it2*512 + tid;
      int n = idx & (NPIX-1);
      int s = seg[idx];
      atomicAdd(&ls[s*4+0], img[(b*3+0)*NPIX+n]);
      atomicAdd(&ls[s*4+1], img[(b*3+1)*NPIX+n]);
      atomicAdd(&ls[s*4+2], img[(b*3+2)*NPIX+n]);
      atomicAdd(&ls[s*4+3], 1.0f);
    }
    __syncthreads();
    for(int j=tid;j<1024;j+=512){
      int s = j>>2, c = j&3;
      float vv = ls[j];
      if(vv != 0.f){
        if(c<3) atomicAdd(&segsum[(b*SS+s)*3+c], vv);
        else    atomicAdd(&counts[b*SS+s], vv);
      }
    }
  }
  bt += 256; gridbar(bar, bt);

  // ---- phase X: x0 = WSproj(concat(feats,z)) -> xp ----
  {
    int b = bid & 3, og = bid >> 2;       // og 0..63
    int i = tid & 255;
    int oo = tid >> 8;                    // 0..1
    float cnt = counts[b*SS+i] + 1e-6f;
    float f0 = segsum[(b*SS+i)*3+0]/cnt;
    float f1 = segsum[(b*SS+i)*3+1]/cnt;
    float f2 = segsum[(b*SS+i)*3+2]/cnt;
    const float* zb = z + b*ZDIM;
    #pragma unroll
    for(int o2=0;o2<2;o2++){
      int o = og*4 + oo*2 + o2;
      const float* wr = pw + o*131;
      float acc = wr[0]*f0 + wr[1]*f1 + wr[2]*f2;
      #pragma unroll 8
      for(int j=0;j<ZDIM;j++) acc += wr[3+j]*zb[j];
      xp[(b*GCH+o)*SS + i] = acc*sProj + pb[o];
    }
  }
  bt += 256; gridbar(bar, bt);

  // ---- 8 graph iterations ----
  for(int it=0; it<NBLKS; it++){
    const float* bw  = bw_all  + it*GCH*GCH;
    const float* bb  = bb_all  + it*GCH;
    const float* a1w = a1w_all + it*512*GCH;
    const float* a1b = a1b_all + it*512;
    const float* a2w = a2w_all + it*512*512;
    const float* a2b = a2b_all + it*512;

    // ---- gemm + A-propagation + node mean (4 ch per block) ----
    {
      int c0 = (bid >> 2)*4;
      int b  = bid & 3;
      int j  = tid & 255;
      int half = tid >> 8;
      wl[half*2+0][j] = bw[(c0+half*2+0)*GCH + j];
      wl[half*2+1][j] = bw[(c0+half*2+1)*GCH + j];
      __syncthreads();
      const float* xb = xp + b*GCH*SS + j;
      float a0 = 0.f, a1 = 0.f;
      int ch = half*2;
      #pragma unroll 8
      for(int k=0;k<GCH;k++){
        float xv = xb[k*SS];
        a0 += wl[ch][k]*xv;
        a1 += wl[ch+1][k]*xv;
      }
      h1l[ch][j]   = a0*sc1 + bb[c0+ch];
      h1l[ch+1][j] = a1*sc1 + bb[c0+ch+1];
      __syncthreads();
      const float* ab = At + b*SS*SS + j;
      float r0 = 0.f, r1 = 0.f;
      #pragma unroll 2
      for(int jj=0;jj<SS;jj+=4){
        float4 h0 = *(const float4*)&h1l[ch][jj];
        float4 h1v = *(const float4*)&h1l[ch+1][jj];
        float av0 = ab[jj*SS], av1 = ab[(jj+1)*SS], av2 = ab[(jj+2)*SS], av3 = ab[(jj+3)*SS];
        r0 += h0.x*av0 + h0.y*av1 + h0.z*av2 + h0.w*av3;
        r1 += h1v.x*av0 + h1v.y*av1 + h1v.z*av2 + h1v.w*av3;
      }
      h2[(b*GCH+c0+ch)*SS + j]   = r0;
      h2[(b*GCH+c0+ch+1)*SS + j] = r1;
      float s0 = r0, s1v = r1;
      for(int off=32; off; off>>=1){ s0 += __shfl_down(s0,off); s1v += __shfl_down(s1v,off); }
      int w3 = (tid >> 6) & 3;
      if((j&63)==0){ red[ch][w3] = s0; red[ch+1][w3] = s1v; }
      __syncthreads();
      if(tid < 4)
        m[b*GCH + c0 + tid] =
          (red[tid][0]+red[tid][1]+red[tid][2]+red[tid][3])*(1.f/256.f);
    }
    bt += 256; gridbar(bar, bt);

    // ---- style L1: rows 2*bid, 2*bid+1; wave = (row, batch) ----
    {
      int r = bid*2 + (wv >> 2);
      int b = wv & 3;
      float4 w4 = ((const float4*)(a1w + r*GCH))[lane];
      float4 m4 = ((const float4*)(m + b*GCH))[lane];
      float p = w4.x*m4.x + w4.y*m4.y + w4.z*m4.z + w4.w*m4.w;
      for(int off=32; off; off>>=1) p += __shfl_xor(p, off);
      if(lane == 0) s1g[b*512 + r] = lrelu(p*sc1 + a1b[r]);
    }
    bt += 256; gridbar(bar, bt);

    // ---- style L2 + AdaIN apply: channel c = bid ----
    {
      int c = bid;
      int b = wv & 3;
      int part = wv >> 2;                 // 0: gamma, 1: beta
      int t = part*256 + c;
      const float4* wr = (const float4*)(a2w + t*512) + lane*2;
      const float4* sr = (const float4*)(s1g + b*512) + lane*2;
      float4 wa = wr[0], wb4 = wr[1], sa = sr[0], sb = sr[1];
      float p = wa.x*sa.x + wa.y*sa.y + wa.z*sa.z + wa.w*sa.w
              + wb4.x*sb.x + wb4.y*sb.y + wb4.z*sb.z + wb4.w*sb.w;
      for(int off=32; off; off>>=1) p += __shfl_xor(p, off);
      if(lane == 0) gbl[part*4 + b] = p*sc2 + a2b[t];
      __syncthreads();
      int b2 = tid >> 7;                  // 0..3
      int j2 = (tid & 127)*2;
      float ga = gbl[b2], be = gbl[4 + b2];
      float2 hv = *(const float2*)&h2[(b2*GCH + c)*SS + j2];
      float2 xv;
      xv.x = lrelu(ga*hv.x + be);
      xv.y = lrelu(ga*hv.y + be);
      *(float2*)&xp[(b2*GCH + c)*SS + j2] = xv;
    }
    bt += 256; gridbar(bar, bt);
  }
}

// ---- v[b][k][s][o] = sum_c wT[k][c][o] * xp[c][s], wT staged in LDS ----
__global__ __launch_bounds__(256) void k_v(const float* __restrict__ xf,
        const float4* __restrict__ wT4, float4* __restrict__ v4){
  int s0 = blockIdx.x*16;           // grid (16,9,4)
  int k  = blockIdx.y;
  int b  = blockIdx.z;
  int tid = threadIdx.x;
  __shared__ float4 wl[64][33];
  __shared__ float xft[256][16];
  for(int t = tid; t < 1024; t += 256){
    int c = t>>2, sf = t&3;
    *(float4*)&xft[c][sf*4] = *(const float4*)(xf + (b*GCH+c)*SS + s0 + sf*4);
  }
  int og = tid & 31, sh = tid >> 5;  // sh 0..7
  const float4* wb = wT4 + (size_t)k*GCH*32;
  float4 a0 = {0.f,0.f,0.f,0.f}, a1 = {0.f,0.f,0.f,0.f};
  for(int ct=0; ct<4; ct++){
    __syncthreads();
    for(int t = tid; t < 2048; t += 256){
      int cc = t>>5, o = t&31;
      wl[cc][o] = wb[(ct*64+cc)*32 + o];
    }
    __syncthreads();
    #pragma unroll 4
    for(int cc=0;cc<64;cc++){
      float4 w = wl[cc][og];
      int c = ct*64+cc;
      float x0v = xft[c][sh];
      float x1v = xft[c][8+sh];
      a0.x += w.x*x0v; a0.y += w.y*x0v; a0.z += w.z*x0v; a0.w += w.w*x0v;
      a1.x += w.x*x1v; a1.y += w.y*x1v; a1.z += w.z*x1v; a1.w += w.w*x1v;
    }
  }
  size_t base = (size_t)(b*9+k)*SS + s0;
  v4[(base + sh)*32 + og]     = a0;
  v4[(base + 8 + sh)*32 + og] = a1;
}

// ---- fused conv1-gather(float4) + conv2 (scalar weights), 8x8 tile ----
// (round-7 version: task-outer, k-inner, g fast-varying, XCD-batch locality)
__global__ __launch_bounds__(256) void k_conv(const float4* __restrict__ v4,
        const int* __restrict__ seg, const float4* __restrict__ b14,
        const float* __restrict__ w2t, float* __restrict__ y2){
  __shared__ float4 y1t4[100*9];    // [pp][8 ch-f4 + pad]
  __shared__ int   segl[144];
  __shared__ float part[768];
  int bid = blockIdx.x;
  int x = bid & 7;
  int b = x >> 1;
  int sub = ((bid >> 3) << 1) + (x & 1);  // 0..4095
  int g = sub & 3;
  int tile = sub >> 2;
  int x0p = (tile & 31)*8, y0p = (tile >> 5)*8;
  int tid = threadIdx.x;
  if(tid < 144){
    int r = tid/12, cc = tid%12;
    int gy = y0p - 2 + r, gx = x0p - 2 + cc;
    segl[tid] = (gy>=0 && gy<256 && gx>=0 && gx<256) ? seg[(b*256+gy)*256+gx] : -1;
  }
  __syncthreads();
  int o4 = tid & 7;
  const float4* vb = v4 + (size_t)(b*9)*SS*32 + g*8 + o4;
  float4 bias = b14[g*8 + o4];
  bool interior = (x0p >= 8 && x0p <= 240 && y0p >= 8 && y0p <= 240);
  if(interior){
    for(int task = tid; task < 800; task += 256){
      int pp = task >> 3;
      int py = pp/10, px = pp - py*10;
      float4 acc = bias;
      #pragma unroll
      for(int k=0;k<9;k++){
        int sidx = segl[(py + k/3)*12 + (px + k%3)];
        float4 vv = vb[(k*SS + sidx)*32];
        acc.x += vv.x; acc.y += vv.y; acc.z += vv.z; acc.w += vv.w;
      }
      float4 val;
      val.x = lrelu(acc.x); val.y = lrelu(acc.y);
      val.z = lrelu(acc.z); val.w = lrelu(acc.w);
      y1t4[pp*9 + o4] = val;
    }
  } else {
    for(int task = tid; task < 800; task += 256){
      int pp = task >> 3;
      int py = pp/10, px = pp - py*10;
      int gy = y0p - 1 + py, gx = x0p - 1 + px;
      bool pix_ok = (gy>=0 && gy<256 && gx>=0 && gx<256);
      float4 acc = bias;
      #pragma unroll
      for(int k=0;k<9;k++){
        int sidx = segl[(py + k/3)*12 + (px + k%3)];
        int sidx0 = sidx < 0 ? 0 : sidx;
        float msk = sidx < 0 ? 0.f : 1.f;
        float4 vv = vb[(k*SS + sidx0)*32];
        acc.x += msk*vv.x; acc.y += msk*vv.y; acc.z += msk*vv.z; acc.w += msk*vv.w;
      }
      float4 val;
      val.x = pix_ok ? lrelu(acc.x) : 0.f;
      val.y = pix_ok ? lrelu(acc.y) : 0.f;
      val.z = pix_ok ? lrelu(acc.z) : 0.f;
      val.w = pix_ok ? lrelu(acc.w) : 0.f;
      y1t4[pp*9 + o4] = val;
    }
  }
  __syncthreads();
  int pxo = tid & 63, sg = tid >> 6;
  int sgu = __builtin_amdgcn_readfirstlane(sg);
  const float* wk0 = w2t + (g*4 + sgu)*24;   // + k*384
  int ty = pxo >> 3, tx = pxo & 7;
  float p0=0.f,p1=0.f,p2=0.f;
  #pragma unroll
  for(int k=0;k<9;k++){
    int pp0 = (ty + k/3)*10 + (tx + k%3);
    float4 ya = y1t4[pp0*9 + sgu*2];
    float4 yb = y1t4[pp0*9 + sgu*2 + 1];
    const float* wk = wk0 + k*384;
    p0 += wk[0]*ya.x + wk[1]*ya.y + wk[2]*ya.z + wk[3]*ya.w
        + wk[4]*yb.x + wk[5]*yb.y + wk[6]*yb.z + wk[7]*yb.w;
    p1 += wk[8]*ya.x + wk[9]*ya.y + wk[10]*ya.z + wk[11]*ya.w
        + wk[12]*yb.x + wk[13]*yb.y + wk[14]*yb.z + wk[15]*yb.w;
    p2 += wk[16]*ya.x + wk[17]*ya.y + wk[18]*ya.z + wk[19]*ya.w
        + wk[20]*yb.x + wk[21]*yb.y + wk[22]*yb.z + wk[23]*yb.w;
  }
  part[tid]     = p0;
  part[256+tid] = p1;
  part[512+tid] = p2;
  __syncthreads();
  if(tid < 64){
    float s0 = part[tid]    +part[tid+64]    +part[tid+128]    +part[tid+192];
    float s1 = part[256+tid]+part[256+tid+64]+part[256+tid+128]+part[256+tid+192];
    float s2 = part[512+tid]+part[512+tid+64]+part[512+tid+128]+part[512+tid+192];
    int gy = y0p + (tid>>3), gx = x0p + (tid&7);
    int nidx = gy*256+gx;
    atomicAdd(&y2[(b*3+0)*NPIX+nidx], s0);
    atomicAdd(&y2[(b*3+1)*NPIX+nidx], s1);
    atomicAdd(&y2[(b*3+2)*NPIX+nidx], s2);
  }
}

// ---- per (b,channel) sum & sumsq, parallel chunks with f64 atomics ----
__global__ void k_stats(const float* __restrict__ y2, double* __restrict__ stats){
  int bc = blockIdx.x;     // 12
  int chunk = blockIdx.y;  // 8
  const float* p = y2 + (size_t)bc*NPIX + chunk*8192;
  int t = threadIdx.x;
  double s=0.0, q=0.0;
  for(int i=t;i<8192;i+=256){ double vv = (double)p[i]; s+=vv; q+=vv*vv; }
  __shared__ double rs[256], rq[256];
  rs[t]=s; rq[t]=q; __syncthreads();
  for(int st=128; st; st>>=1){ if(t<st){rs[t]+=rs[t+st]; rq[t]+=rq[t+st];} __syncthreads(); }
  if(t==0){ atomicAdd(&stats[bc*2], rs[0]); atomicAdd(&stats[bc*2+1], rq[0]); }
}

// ---- instance norm + tanh ----
__global__ void k_norm(const float* __restrict__ y2, const double* __restrict__ stats,
                       float* __restrict__ out){
  int bu = (blockIdx.x*256) >> 16;           // uniform per block
  double mu  = stats[bu*2+0] * (1.0/65536.0);
  double ex2 = stats[bu*2+1] * (1.0/65536.0);
  double var = ex2 - mu*mu;
  float inv = (float)(1.0/sqrt(var + 1e-5));
  float mf = (float)mu;
  int idx = blockIdx.x*256+threadIdx.x;
  out[idx] = tanhf((y2[idx]-mf)*inv);
}

extern "C" void kernel_launch(void* const* d_in, const int* in_sizes, int n_in,
                              void* d_out, int out_size, void* d_ws, size_t ws_size,
                              hipStream_t stream) {
  const float* z   = (const float*)d_in[0];
  const float* img = (const float*)d_in[1];
  const int*   seg = (const int*)d_in[2];
  const float* A   = (const float*)d_in[3];
  const float* pw  = (const float*)d_in[4];
  const float* pb  = (const float*)d_in[5];
  const float* bw  = (const float*)d_in[6];
  const float* bb  = (const float*)d_in[7];
  const float* a1w = (const float*)d_in[8];
  const float* a1b = (const float*)d_in[9];
  const float* a2w = (const float*)d_in[10];
  const float* a2b = (const float*)d_in[11];
  const float* w1  = (const float*)d_in[12];
  const float* b1  = (const float*)d_in[13];
  const float* w2  = (const float*)d_in[14];
  const float* b2  = (const float*)d_in[15]; (void)b2; // cancels under InstanceNorm
  float* out = (float*)d_out;

  float* ws = (float*)d_ws;
  float* segsum = ws;                    // 3072
  float* counts = ws + 3072;             // 1024 -> 4096
  float* m      = ws + 4096;             // 1024 -> 5120
  float* s1g    = ws + 5120;             // 2048 -> 7168
  double* stats = (double*)(ws + 7168);  // 24 doubles -> 7216
  int*   bar    = (int*)(ws + 7216);     // 16 ints -> 7232, pad to 7296
  float* xp  = ws + 7296;                // 262144
  float* h2  = xp + 262144;              // 262144
  float* At  = h2 + 262144;              // 262144
  float* wT  = At + 262144;              // 294912
  float* v   = wT + 294912;              // 1179648
  float* y2  = v + 1179648;              // 786432
  float* w2t = y2 + 786432;              // 3456   (end ~12.2 MB)

  hipMemsetAsync(ws, 0, 7296*sizeof(float), stream);     // sums + stats + barrier
  hipMemsetAsync(y2, 0, 786432*sizeof(float), stream);   // conv2 accumulator

  float sProj = (float)sqrt(2.0/131.0);
  float s256  = (float)sqrt(2.0/256.0);
  float s512  = (float)sqrt(2.0/512.0);

  k_prep<<<256 + 1166, 256, 0, stream>>>(A, w1, w2, At, wT, w2t);
  k_mega<<<256, 512, 0, stream>>>(img, seg, segsum, counts, z, pw, pb, At,
                                  bw, bb, a1w, a1b, a2w, a2b,
                                  xp, h2, m, s1g, bar, sProj, s256, s512);
  k_v   <<<dim3(16,9,4), 256, 0, stream>>>(xp, (const float4*)wT, (float4*)v);
  k_conv<<<16384, 256, 0, stream>>>((const float4*)v, seg, (const float4*)b1, w2t, y2);
  k_stats<<<dim3(12,8), 256, 0, stream>>>(y2, stats);
  k_norm<<<3072, 256, 0, stream>>>(y2, stats, out);
}

// Round 10
// 372.902 us; speedup vs baseline: 1.7137x; 1.7137x over previous
//
#include <hip/hip_runtime.h>
#include <cmath>

#define BB 4
#define SS 256
#define ZDIM 128
#define GCH 256
#define NBLKS 8
#define NPIX 65536   // 256*256
#define U1C 128      // GC/2

__device__ __forceinline__ float lrelu(float x){ return x >= 0.f ? x : 0.2f*x; }

// ---- segment mean pooling (LDS histogram, then global atomics) ----
__global__ void k_pool(const float* __restrict__ img, const int* __restrict__ seg,
                       float* __restrict__ segsum, float* __restrict__ counts){
  __shared__ float ls[SS*4];
  int t = threadIdx.x;
  for(int j=t;j<SS*4;j+=256) ls[j]=0.f;
  __syncthreads();
  int b = blockIdx.x >> 6;            // 64 blocks per batch
  int base = blockIdx.x*1024;
  for(int it=0; it<4; it++){
    int idx = base + it*256 + t;
    int n = idx & (NPIX-1);
    int s = seg[idx];
    atomicAdd(&ls[s*4+0], img[(b*3+0)*NPIX+n]);
    atomicAdd(&ls[s*4+1], img[(b*3+1)*NPIX+n]);
    atomicAdd(&ls[s*4+2], img[(b*3+2)*NPIX+n]);
    atomicAdd(&ls[s*4+3], 1.0f);
  }
  __syncthreads();
  for(int j=t;j<SS*4;j+=256){
    int s = j>>2, c = j&3;
    float vv = ls[j];
    if(vv != 0.f){
      if(c<3) atomicAdd(&segsum[(b*SS+s)*3+c], vv);
      else    atomicAdd(&counts[b*SS+s], vv);
    }
  }
}

// ---- prep: A -> At2 packed transpose (blocks 0..255), wT, w2t ----
// At2[b][jj>>2][i][jj&3] = A[b][i][jj]   (float4 over 4 consecutive jj)
__global__ __launch_bounds__(256) void k_prep(const float* __restrict__ A,
        const float* __restrict__ w1, const float* __restrict__ w2,
        float* __restrict__ At2, float* __restrict__ wT, float* __restrict__ w2t){
  int bid = blockIdx.x;
  if(bid < 256){
    __shared__ float t[32][33];
    int b = bid >> 6;
    int bx = (bid & 7)*32, by = ((bid >> 3) & 7)*32;
    int lx = threadIdx.x & 31, ly4 = (threadIdx.x >> 5)*4;
    #pragma unroll
    for(int r=0;r<4;r++)
      t[ly4+r][lx] = A[(b<<16) + ((by+ly4+r)<<8) + bx + lx];
    __syncthreads();
    #pragma unroll
    for(int r=0;r<4;r++){
      int jj = bx + ly4 + r;
      int i  = by + lx;
      At2[(b<<16) + ((jj>>2)<<10) + (i<<2) + (jj&3)] = t[lx][ly4+r];
    }
  } else {
    int idx = (bid-256)*256 + threadIdx.x;
    if(idx < 294912){
      int o = idx & 127; int r = idx >> 7; int c = r & 255; int k = r >> 8;
      wT[idx] = w1[(o*GCH + c)*9 + k];
    } else if(idx < 294912 + 3456){
      int t2 = idx - 294912;
      int cc = t2 & 7;
      int oc = (t2 >> 3) % 3;
      int sg = (t2 / 24) & 3;
      int g  = (t2 / 96) & 3;
      int k  = t2 / 384;
      w2t[t2] = w2[oc*1152 + (g*32 + sg*8 + cc)*9 + k];
    }
  }
}

// ---- x0 = WSproj(concat(feats, z)) -> xp2 (packed float4 over channels) ----
__global__ __launch_bounds__(256) void k_x0(const float* __restrict__ segsum,
        const float* __restrict__ counts, const float* __restrict__ z,
        const float* __restrict__ pw, const float* __restrict__ pb,
        float sc, float4* __restrict__ xp2){
  int og = blockIdx.x;              // 0..63 (channel group of 4)
  int b  = blockIdx.y;
  int i  = threadIdx.x;             // node
  float cnt = counts[b*SS+i] + 1e-6f;
  float f0 = segsum[(b*SS+i)*3+0]/cnt;
  float f1 = segsum[(b*SS+i)*3+1]/cnt;
  float f2 = segsum[(b*SS+i)*3+2]/cnt;
  const float* zb = z + b*ZDIM;
  float vals[4];
  #pragma unroll
  for(int oo=0;oo<4;oo++){
    int o = og*4 + oo;
    const float* wr = pw + o*131;
    float acc = wr[0]*f0 + wr[1]*f1 + wr[2]*f2;
    #pragma unroll 8
    for(int j=0;j<ZDIM;j++) acc += wr[3+j]*zb[j];
    vals[oo] = acc*sc + pb[o];
  }
  float4 o4 = {vals[0], vals[1], vals[2], vals[3]};
  xp2[(b*64+og)*256 + i] = o4;
}

// ---- gemm + A-propagation + node mean: 4 ch/block, 512 thr, float4 loads ----
__global__ __launch_bounds__(512) void k_gemm(const float4* __restrict__ xp2,
        const float* __restrict__ bw, const float* __restrict__ bb,
        const float4* __restrict__ At2, float sc,
        float* __restrict__ h2, float* __restrict__ m){
  int c0 = blockIdx.x*4;
  int b  = blockIdx.y;
  int tid = threadIdx.x;
  int j  = tid & 255;
  int half = tid >> 8;
  int ch0 = c0 + half*2;
  __shared__ float4 wl4[4][64];
  __shared__ float4 h1l4[4][66];
  __shared__ float red[4][4];
  for(int t = tid; t < 1024; t += 512){
    int row = t >> 8, jj = t & 255;
    ((float*)&wl4[row][0])[jj] = bw[(c0+row)*GCH + jj];
  }
  __syncthreads();
  const float4* xb = xp2 + (b*64)*256 + j;
  float a0 = 0.f, a1 = 0.f;
  int r0i = half*2, r1i = half*2+1;
  #pragma unroll 8
  for(int kg=0;kg<64;kg++){
    float4 x = xb[kg*256];
    float4 w0 = wl4[r0i][kg];
    float4 w1 = wl4[r1i][kg];
    a0 += w0.x*x.x + w0.y*x.y + w0.z*x.z + w0.w*x.w;
    a1 += w1.x*x.x + w1.y*x.y + w1.z*x.z + w1.w*x.w;
  }
  ((float*)&h1l4[r0i][0])[j] = a0*sc + bb[ch0];
  ((float*)&h1l4[r1i][0])[j] = a1*sc + bb[ch0+1];
  __syncthreads();
  const float4* ab = At2 + (b*64)*256 + j;
  float r0 = 0.f, r1 = 0.f;
  #pragma unroll 8
  for(int kg=0;kg<64;kg++){
    float4 a = ab[kg*256];
    float4 h0 = h1l4[r0i][kg];
    float4 h1 = h1l4[r1i][kg];
    r0 += a.x*h0.x + a.y*h0.y + a.z*h0.z + a.w*h0.w;
    r1 += a.x*h1.x + a.y*h1.y + a.z*h1.z + a.w*h1.w;
  }
  h2[(b*GCH+ch0)*SS + j]   = r0;
  h2[(b*GCH+ch0+1)*SS + j] = r1;
  float s0 = r0, s1v = r1;
  for(int off=32; off; off>>=1){ s0 += __shfl_down(s0,off); s1v += __shfl_down(s1v,off); }
  int w3 = (tid >> 6) & 3;
  if((j&63)==0){ red[r0i][w3] = s0; red[r1i][w3] = s1v; }
  __syncthreads();
  if(tid < 4)
    m[b*GCH + c0 + tid] =
      (red[tid][0]+red[tid][1]+red[tid][2]+red[tid][3])*(1.f/256.f);
}

// ---- fused style L1 + L2 + AdaIN apply: 32 blocks x 512 threads ----
__global__ __launch_bounds__(512) void k_s12(const float* __restrict__ m,
        const float* __restrict__ a1w, const float* __restrict__ a1b,
        const float* __restrict__ a2w, const float* __restrict__ a2b,
        const float* __restrict__ h2, float sc1, float sc2,
        float4* __restrict__ xp2){
  int q = blockIdx.x;               // 0..31
  int tid = threadIdx.x;
  int lane = tid & 63, wv = tid >> 6;      // wv 0..7
  int grp = lane >> 3, ll = lane & 7;
  __shared__ float4 ml4[256];       // m: [b*64 + i]
  __shared__ float s1l[4][512];     // s1 stored at [(row&7)*64 + (row>>3)]
  __shared__ float gbl[4][16];
  if(tid < 256) ml4[tid] = ((const float4*)m)[tid];
  __syncthreads();
  #pragma unroll 2
  for(int pass=0; pass<8; pass++){
    int row = wv*64 + pass*8 + grp;
    const float4* ar = (const float4*)(a1w + row*GCH) + ll;
    float p0=0.f,p1=0.f,p2=0.f,p3=0.f;
    #pragma unroll
    for(int j=0;j<8;j++){
      float4 w4 = ar[j*8];
      float4 m0 = ml4[0*64 + j*8 + ll];
      float4 m1 = ml4[1*64 + j*8 + ll];
      float4 m2 = ml4[2*64 + j*8 + ll];
      float4 m3 = ml4[3*64 + j*8 + ll];
      p0 += w4.x*m0.x + w4.y*m0.y + w4.z*m0.z + w4.w*m0.w;
      p1 += w4.x*m1.x + w4.y*m1.y + w4.z*m1.z + w4.w*m1.w;
      p2 += w4.x*m2.x + w4.y*m2.y + w4.z*m2.z + w4.w*m2.w;
      p3 += w4.x*m3.x + w4.y*m3.y + w4.z*m3.z + w4.w*m3.w;
    }
    #pragma unroll
    for(int off=1; off<8; off<<=1){
      p0 += __shfl_xor(p0,off); p1 += __shfl_xor(p1,off);
      p2 += __shfl_xor(p2,off); p3 += __shfl_xor(p3,off);
    }
    if(ll == 0){
      float bv = a1b[row];
      int sidx = ((row & 7) << 6) + (row >> 3);
      s1l[0][sidx] = lrelu(p0*sc1 + bv);
      s1l[1][sidx] = lrelu(p1*sc1 + bv);
      s1l[2][sidx] = lrelu(p2*sc1 + bv);
      s1l[3][sidx] = lrelu(p3*sc1 + bv);
    }
  }
  __syncthreads();
  float sA[4][8];
  #pragma unroll
  for(int b=0;b<4;b++)
    #pragma unroll
    for(int j=0;j<8;j++) sA[b][j] = s1l[b][j*64 + lane];
  #pragma unroll
  for(int r=0;r<2;r++){
    int ridx = wv*2 + r;            // 0..15
    int cc = ridx & 7;
    int t = (ridx < 8) ? (q*8 + cc) : (256 + q*8 + cc);
    const float* wr = a2w + t*512 + lane*8;
    float4 wa = *(const float4*)wr;
    float4 wb4 = *(const float4*)(wr+4);
    float p0 = wa.x*sA[0][0]+wa.y*sA[0][1]+wa.z*sA[0][2]+wa.w*sA[0][3]
             + wb4.x*sA[0][4]+wb4.y*sA[0][5]+wb4.z*sA[0][6]+wb4.w*sA[0][7];
    float p1 = wa.x*sA[1][0]+wa.y*sA[1][1]+wa.z*sA[1][2]+wa.w*sA[1][3]
             + wb4.x*sA[1][4]+wb4.y*sA[1][5]+wb4.z*sA[1][6]+wb4.w*sA[1][7];
    float p2 = wa.x*sA[2][0]+wa.y*sA[2][1]+wa.z*sA[2][2]+wa.w*sA[2][3]
             + wb4.x*sA[2][4]+wb4.y*sA[2][5]+wb4.z*sA[2][6]+wb4.w*sA[2][7];
    float p3 = wa.x*sA[3][0]+wa.y*sA[3][1]+wa.z*sA[3][2]+wa.w*sA[3][3]
             + wb4.x*sA[3][4]+wb4.y*sA[3][5]+wb4.z*sA[3][6]+wb4.w*sA[3][7];
    for(int off=32; off; off>>=1){
      p0 += __shfl_xor(p0,off); p1 += __shfl_xor(p1,off);
      p2 += __shfl_xor(p2,off); p3 += __shfl_xor(p3,off);
    }
    if(lane < 4){
      float p = lane==0 ? p0 : lane==1 ? p1 : lane==2 ? p2 : p3;
      gbl[lane][ridx] = p*sc2 + a2b[t];
    }
  }
  __syncthreads();
  // apply AdaIN + leaky: 8 channels = 2 float4 groups; write packed xp2
  int j = tid & 255;
  int cg2 = tid >> 8;               // 0..1
  int cbase = q*8 + cg2*4;
  int cg = cbase >> 2;              // q*2 + cg2
  #pragma unroll
  for(int b=0;b<4;b++){
    float4 o;
    o.x = lrelu(gbl[b][cg2*4+0]*h2[(b*GCH + cbase+0)*SS + j] + gbl[b][8+cg2*4+0]);
    o.y = lrelu(gbl[b][cg2*4+1]*h2[(b*GCH + cbase+1)*SS + j] + gbl[b][8+cg2*4+1]);
    o.z = lrelu(gbl[b][cg2*4+2]*h2[(b*GCH + cbase+2)*SS + j] + gbl[b][8+cg2*4+2]);
    o.w = lrelu(gbl[b][cg2*4+3]*h2[(b*GCH + cbase+3)*SS + j] + gbl[b][8+cg2*4+3]);
    xp2[(b*64 + cg)*256 + j] = o;
  }
}

// ---- v[b][k][s][o] = sum_c wT[k][c][o] * xp[c][s], wT staged in LDS ----
__global__ __launch_bounds__(256) void k_v(const float4* __restrict__ xp2,
        const float4* __restrict__ wT4, float4* __restrict__ v4){
  int s0 = blockIdx.x*16;           // grid (16,9,4)
  int k  = blockIdx.y;
  int b  = blockIdx.z;
  int tid = threadIdx.x;
  __shared__ float4 wl[64][33];
  __shared__ float xft[256][17];
  for(int t = tid; t < 1024; t += 256){
    int cg = t >> 4, si = t & 15;
    float4 xv = xp2[(b*64 + cg)*256 + s0 + si];
    xft[cg*4+0][si] = xv.x;
    xft[cg*4+1][si] = xv.y;
    xft[cg*4+2][si] = xv.z;
    xft[cg*4+3][si] = xv.w;
  }
  int og = tid & 31, sh = tid >> 5;  // sh 0..7
  const float4* wb = wT4 + (size_t)k*GCH*32;
  float4 a0 = {0.f,0.f,0.f,0.f}, a1 = {0.f,0.f,0.f,0.f};
  for(int ct=0; ct<4; ct++){
    __syncthreads();
    for(int t = tid; t < 2048; t += 256){
      int cc = t>>5, o = t&31;
      wl[cc][o] = wb[(ct*64+cc)*32 + o];
    }
    __syncthreads();
    #pragma unroll 4
    for(int cc=0;cc<64;cc++){
      float4 w = wl[cc][og];
      int c = ct*64+cc;
      float x0v = xft[c][sh];
      float x1v = xft[c][8+sh];
      a0.x += w.x*x0v; a0.y += w.y*x0v; a0.z += w.z*x0v; a0.w += w.w*x0v;
      a1.x += w.x*x1v; a1.y += w.y*x1v; a1.z += w.z*x1v; a1.w += w.w*x1v;
    }
  }
  size_t base = (size_t)(b*9+k)*SS + s0;
  v4[(base + sh)*32 + og]     = a0;
  v4[(base + 8 + sh)*32 + og] = a1;
}

// ---- fused conv1-gather(float4) + conv2 (scalar weights), 8x8 tile ----
// (round-7 proven version: task-outer, g fast-varying, XCD-batch locality)
__global__ __launch_bounds__(256) void k_conv(const float4* __restrict__ v4,
        const int* __restrict__ seg, const float4* __restrict__ b14,
        const float* __restrict__ w2t, float* __restrict__ y2){
  __shared__ float4 y1t4[100*9];    // [pp][8 ch-f4 + pad]
  __shared__ int   segl[144];
  __shared__ float part[768];
  int bid = blockIdx.x;
  int x = bid & 7;
  int b = x >> 1;
  int sub = ((bid >> 3) << 1) + (x & 1);  // 0..4095
  int g = sub & 3;
  int tile = sub >> 2;
  int x0p = (tile & 31)*8, y0p = (tile >> 5)*8;
  int tid = threadIdx.x;
  if(tid < 144){
    int r = tid/12, cc = tid%12;
    int gy = y0p - 2 + r, gx = x0p - 2 + cc;
    segl[tid] = (gy>=0 && gy<256 && gx>=0 && gx<256) ? seg[(b*256+gy)*256+gx] : -1;
  }
  __syncthreads();
  int o4 = tid & 7;
  const float4* vb = v4 + (size_t)(b*9)*SS*32 + g*8 + o4;
  float4 bias = b14[g*8 + o4];
  bool interior = (x0p >= 8 && x0p <= 240 && y0p >= 8 && y0p <= 240);
  if(interior){
    for(int task = tid; task < 800; task += 256){
      int pp = task >> 3;
      int py = pp/10, px = pp - py*10;
      float4 acc = bias;
      #pragma unroll
      for(int k=0;k<9;k++){
        int sidx = segl[(py + k/3)*12 + (px + k%3)];
        float4 vv = vb[(k*SS + sidx)*32];
        acc.x += vv.x; acc.y += vv.y; acc.z += vv.z; acc.w += vv.w;
      }
      float4 val;
      val.x = lrelu(acc.x); val.y = lrelu(acc.y);
      val.z = lrelu(acc.z); val.w = lrelu(acc.w);
      y1t4[pp*9 + o4] = val;
    }
  } else {
    for(int task = tid; task < 800; task += 256){
      int pp = task >> 3;
      int py = pp/10, px = pp - py*10;
      int gy = y0p - 1 + py, gx = x0p - 1 + px;
      bool pix_ok = (gy>=0 && gy<256 && gx>=0 && gx<256);
      float4 acc = bias;
      #pragma unroll
      for(int k=0;k<9;k++){
        int sidx = segl[(py + k/3)*12 + (px + k%3)];
        int sidx0 = sidx < 0 ? 0 : sidx;
        float msk = sidx < 0 ? 0.f : 1.f;
        float4 vv = vb[(k*SS + sidx0)*32];
        acc.x += msk*vv.x; acc.y += msk*vv.y; acc.z += msk*vv.z; acc.w += msk*vv.w;
      }
      float4 val;
      val.x = pix_ok ? lrelu(acc.x) : 0.f;
      val.y = pix_ok ? lrelu(acc.y) : 0.f;
      val.z = pix_ok ? lrelu(acc.z) : 0.f;
      val.w = pix_ok ? lrelu(acc.w) : 0.f;
      y1t4[pp*9 + o4] = val;
    }
  }
  __syncthreads();
  int pxo = tid & 63, sg = tid >> 6;
  int sgu = __builtin_amdgcn_readfirstlane(sg);
  const float* wk0 = w2t + (g*4 + sgu)*24;   // + k*384
  int ty = pxo >> 3, tx = pxo & 7;
  float p0=0.f,p1=0.f,p2=0.f;
  #pragma unroll
  for(int k=0;k<9;k++){
    int pp0 = (ty + k/3)*10 + (tx + k%3);
    float4 ya = y1t4[pp0*9 + sgu*2];
    float4 yb = y1t4[pp0*9 + sgu*2 + 1];
    const float* wk = wk0 + k*384;
    p0 += wk[0]*ya.x + wk[1]*ya.y + wk[2]*ya.z + wk[3]*ya.w
        + wk[4]*yb.x + wk[5]*yb.y + wk[6]*yb.z + wk[7]*yb.w;
    p1 += wk[8]*ya.x + wk[9]*ya.y + wk[10]*ya.z + wk[11]*ya.w
        + wk[12]*yb.x + wk[13]*yb.y + wk[14]*yb.z + wk[15]*yb.w;
    p2 += wk[16]*ya.x + wk[17]*ya.y + wk[18]*ya.z + wk[19]*ya.w
        + wk[20]*yb.x + wk[21]*yb.y + wk[22]*yb.z + wk[23]*yb.w;
  }
  part[tid]     = p0;
  part[256+tid] = p1;
  part[512+tid] = p2;
  __syncthreads();
  if(tid < 64){
    float s0 = part[tid]    +part[tid+64]    +part[tid+128]    +part[tid+192];
    float s1 = part[256+tid]+part[256+tid+64]+part[256+tid+128]+part[256+tid+192];
    float s2 = part[512+tid]+part[512+tid+64]+part[512+tid+128]+part[512+tid+192];
    int gy = y0p + (tid>>3), gx = x0p + (tid&7);
    int nidx = gy*256+gx;
    atomicAdd(&y2[(b*3+0)*NPIX+nidx], s0);
    atomicAdd(&y2[(b*3+1)*NPIX+nidx], s1);
    atomicAdd(&y2[(b*3+2)*NPIX+nidx], s2);
  }
}

// ---- per (b,channel) sum & sumsq, parallel chunks with f64 atomics ----
__global__ void k_stats(const float* __restrict__ y2, double* __restrict__ stats){
  int bc = blockIdx.x;     // 12
  int chunk = blockIdx.y;  // 8
  const float* p = y2 + (size_t)bc*NPIX + chunk*8192;
  int t = threadIdx.x;
  double s=0.0, q=0.0;
  for(int i=t;i<8192;i+=256){ double vv = (double)p[i]; s+=vv; q+=vv*vv; }
  __shared__ double rs[256], rq[256];
  rs[t]=s; rq[t]=q; __syncthreads();
  for(int st=128; st; st>>=1){ if(t<st){rs[t]+=rs[t+st]; rq[t]+=rq[t+st];} __syncthreads(); }
  if(t==0){ atomicAdd(&stats[bc*2], rs[0]); atomicAdd(&stats[bc*2+1], rq[0]); }
}

// ---- instance norm + tanh ----
__global__ void k_norm(const float* __restrict__ y2, const double* __restrict__ stats,
                       float* __restrict__ out){
  int bu = (blockIdx.x*256) >> 16;           // uniform per block
  double mu  = stats[bu*2+0] * (1.0/65536.0);
  double ex2 = stats[bu*2+1] * (1.0/65536.0);
  double var = ex2 - mu*mu;
  float inv = (float)(1.0/sqrt(var + 1e-5));
  float mf = (float)mu;
  int idx = blockIdx.x*256+threadIdx.x;
  out[idx] = tanhf((y2[idx]-mf)*inv);
}

extern "C" void kernel_launch(void* const* d_in, const int* in_sizes, int n_in,
                              void* d_out, int out_size, void* d_ws, size_t ws_size,
                              hipStream_t stream) {
  const float* z   = (const float*)d_in[0];
  const float* img = (const float*)d_in[1];
  const int*   seg = (const int*)d_in[2];
  const float* A   = (const float*)d_in[3];
  const float* pw  = (const float*)d_in[4];
  const float* pb  = (const float*)d_in[5];
  const float* bw  = (const float*)d_in[6];
  const float* bb  = (const float*)d_in[7];
  const float* a1w = (const float*)d_in[8];
  const float* a1b = (const float*)d_in[9];
  const float* a2w = (const float*)d_in[10];
  const float* a2b = (const float*)d_in[11];
  const float* w1  = (const float*)d_in[12];
  const float* b1  = (const float*)d_in[13];
  const float* w2  = (const float*)d_in[14];
  const float* b2  = (const float*)d_in[15]; (void)b2; // cancels under InstanceNorm
  float* out = (float*)d_out;

  float* ws = (float*)d_ws;
  float* segsum = ws;                    // 3072
  float* counts = ws + 3072;             // 1024 -> 4096
  float* m      = ws + 4096;             // 1024 -> 5120
  double* stats = (double*)(ws + 5120);  // 24 doubles -> 5168, pad to 5248
  float* xp2 = ws + 5248;                // 262144 (16B-aligned: 5248*4 % 16 == 0)
  float* h2  = xp2 + 262144;             // 262144
  float* At2 = h2 + 262144;              // 262144
  float* wT  = At2 + 262144;             // 294912
  float* v   = wT + 294912;              // 1179648
  float* y2  = v + 1179648;              // 786432
  float* w2t = y2 + 786432;              // 3456   (end ~12.2 MB)

  hipMemsetAsync(ws, 0, 5248*sizeof(float), stream);     // sums + stats
  hipMemsetAsync(y2, 0, 786432*sizeof(float), stream);   // conv2 accumulator

  float sProj = (float)sqrt(2.0/131.0);
  float s256  = (float)sqrt(2.0/256.0);
  float s512  = (float)sqrt(2.0/512.0);

  k_pool<<<256, 256, 0, stream>>>(img, seg, segsum, counts);
  k_prep<<<256 + 1166, 256, 0, stream>>>(A, w1, w2, At2, wT, w2t);
  k_x0  <<<dim3(64,4), 256, 0, stream>>>(segsum, counts, z, pw, pb, sProj,
                                         (float4*)xp2);

  for(int blk=0; blk<NBLKS; blk++){
    k_gemm<<<dim3(64,4), 512, 0, stream>>>((const float4*)xp2,
                                           bw + blk*GCH*GCH, bb + blk*GCH,
                                           (const float4*)At2, s256, h2, m);
    k_s12 <<<32, 512, 0, stream>>>(m, a1w + blk*512*GCH, a1b + blk*512,
                                   a2w + blk*512*512, a2b + blk*512,
                                   h2, s256, s512, (float4*)xp2);
  }

  k_v   <<<dim3(16,9,4), 256, 0, stream>>>((const float4*)xp2, (const float4*)wT,
                                           (float4*)v);
  k_conv<<<16384, 256, 0, stream>>>((const float4*)v, seg, (const float4*)b1, w2t, y2);
  k_stats<<<dim3(12,8), 256, 0, stream>>>(y2, stats);
  k_norm<<<3072, 256, 0, stream>>>(y2, stats, out);
}

// Round 11
// 371.260 us; speedup vs baseline: 1.7212x; 1.0044x over previous
//
#include <hip/hip_runtime.h>
#include <cmath>

#define BB 4
#define SS 256
#define ZDIM 128
#define GCH 256
#define NBLKS 8
#define NPIX 65536   // 256*256
#define U1C 128      // GC/2

__device__ __forceinline__ float lrelu(float x){ return x >= 0.f ? x : 0.2f*x; }

// ---- fused: pool (blocks 0..255) + A packed transpose (256..511) + wT/w2t ----
__global__ __launch_bounds__(256) void k_pp(const float* __restrict__ img,
        const int* __restrict__ seg, float* __restrict__ segsum,
        float* __restrict__ counts, const float* __restrict__ A,
        const float* __restrict__ w1, const float* __restrict__ w2,
        float* __restrict__ At2, float* __restrict__ wT, float* __restrict__ w2t){
  int bid = blockIdx.x;
  int tid = threadIdx.x;
  if(bid < 256){
    __shared__ float ls[SS*4];
    for(int j=tid;j<SS*4;j+=256) ls[j]=0.f;
    __syncthreads();
    int b = bid >> 6;
    int base = bid*1024;
    for(int it=0; it<4; it++){
      int idx = base + it*256 + tid;
      int n = idx & (NPIX-1);
      int s = seg[idx];
      atomicAdd(&ls[s*4+0], img[(b*3+0)*NPIX+n]);
      atomicAdd(&ls[s*4+1], img[(b*3+1)*NPIX+n]);
      atomicAdd(&ls[s*4+2], img[(b*3+2)*NPIX+n]);
      atomicAdd(&ls[s*4+3], 1.0f);
    }
    __syncthreads();
    for(int j=tid;j<SS*4;j+=256){
      int s = j>>2, c = j&3;
      float vv = ls[j];
      if(vv != 0.f){
        if(c<3) atomicAdd(&segsum[(b*SS+s)*3+c], vv);
        else    atomicAdd(&counts[b*SS+s], vv);
      }
    }
  } else if(bid < 512){
    __shared__ float t[32][33];
    int sb = bid - 256;
    int b = sb >> 6;
    int bx = (sb & 7)*32, by = ((sb >> 3) & 7)*32;
    int lx = tid & 31, ly4 = (tid >> 5)*4;
    #pragma unroll
    for(int r=0;r<4;r++)
      t[ly4+r][lx] = A[(b<<16) + ((by+ly4+r)<<8) + bx + lx];
    __syncthreads();
    #pragma unroll
    for(int r=0;r<4;r++){
      int jj = bx + ly4 + r;
      int i  = by + lx;
      At2[(b<<16) + ((jj>>2)<<10) + (i<<2) + (jj&3)] = t[lx][ly4+r];
    }
  } else {
    int idx = (bid-512)*256 + tid;
    if(idx < 294912){
      int o = idx & 127; int r = idx >> 7; int c = r & 255; int k = r >> 8;
      wT[idx] = w1[(o*GCH + c)*9 + k];
    } else if(idx < 294912 + 3456){
      int t2 = idx - 294912;
      int cc = t2 & 7;
      int oc = (t2 >> 3) % 3;
      int sg = (t2 / 24) & 3;
      int g  = (t2 / 96) & 3;
      int k  = t2 / 384;
      w2t[t2] = w2[oc*1152 + (g*32 + sg*8 + cc)*9 + k];
    }
  }
}

// ---- x0 = WSproj(concat(feats, z)) -> xp2 (packed float4 over channels) ----
__global__ __launch_bounds__(256) void k_x0(const float* __restrict__ segsum,
        const float* __restrict__ counts, const float* __restrict__ z,
        const float* __restrict__ pw, const float* __restrict__ pb,
        float sc, float4* __restrict__ xp2){
  int og = blockIdx.x;              // 0..63 (channel group of 4)
  int b  = blockIdx.y;
  int i  = threadIdx.x;             // node
  float cnt = counts[b*SS+i] + 1e-6f;
  float f0 = segsum[(b*SS+i)*3+0]/cnt;
  float f1 = segsum[(b*SS+i)*3+1]/cnt;
  float f2 = segsum[(b*SS+i)*3+2]/cnt;
  const float* zb = z + b*ZDIM;
  float vals[4];
  #pragma unroll
  for(int oo=0;oo<4;oo++){
    int o = og*4 + oo;
    const float* wr = pw + o*131;
    float acc = wr[0]*f0 + wr[1]*f1 + wr[2]*f2;
    #pragma unroll 8
    for(int j=0;j<ZDIM;j++) acc += wr[3+j]*zb[j];
    vals[oo] = acc*sc + pb[o];
  }
  float4 o4 = {vals[0], vals[1], vals[2], vals[3]};
  xp2[(b*64+og)*256 + i] = o4;
}

// ---- gemm + A-propagation + node mean: 4 ch/block, 512 thr, K-split halves ----
__global__ __launch_bounds__(512) void k_gemm(const float4* __restrict__ xp2,
        const float* __restrict__ bw, const float* __restrict__ bb,
        const float4* __restrict__ At2, float sc,
        float* __restrict__ h2, float* __restrict__ m){
  int c0 = blockIdx.x*4;
  int b  = blockIdx.y;
  int tid = threadIdx.x;
  int j  = tid & 255;
  int h  = tid >> 8;               // K-half
  __shared__ float4 wl4[4][64];    // weights, 4 KB
  __shared__ float ps[8][260];     // partials [ch*2+h][j], 8.1 KB
  __shared__ float4 h1l4[4][66];   // h1 packed, 4.2 KB
  __shared__ float red[4][4];
  for(int t = tid; t < 1024; t += 512){
    int row = t >> 8, jj = t & 255;
    ((float*)&wl4[row][0])[jj] = bw[(c0+row)*GCH + jj];
  }
  __syncthreads();
  // gemm partial over K-half h
  {
    const float4* xb = xp2 + (b*64 + h*32)*256 + j;
    float a0=0.f, a1=0.f, a2=0.f, a3=0.f;
    #pragma unroll 8
    for(int kg=0; kg<32; kg++){
      float4 x  = xb[kg*256];
      float4 w0 = wl4[0][h*32+kg];
      float4 w1v= wl4[1][h*32+kg];
      float4 w2v= wl4[2][h*32+kg];
      float4 w3 = wl4[3][h*32+kg];
      a0 += w0.x*x.x + w0.y*x.y + w0.z*x.z + w0.w*x.w;
      a1 += w1v.x*x.x + w1v.y*x.y + w1v.z*x.z + w1v.w*x.w;
      a2 += w2v.x*x.x + w2v.y*x.y + w2v.z*x.z + w2v.w*x.w;
      a3 += w3.x*x.x + w3.y*x.y + w3.z*x.z + w3.w*x.w;
    }
    ps[0+h][j] = a0; ps[2+h][j] = a1; ps[4+h][j] = a2; ps[6+h][j] = a3;
  }
  __syncthreads();
  if(tid < 256){
    #pragma unroll
    for(int ch=0;ch<4;ch++){
      float vv = (ps[ch*2][tid] + ps[ch*2+1][tid])*sc + bb[c0+ch];
      ((float*)&h1l4[ch][0])[tid] = vv;
    }
  }
  __syncthreads();
  // propagation partial over jj-half h
  {
    const float4* ab = At2 + (b*64 + h*32)*256 + j;
    float r0=0.f, r1=0.f, r2=0.f, r3=0.f;
    #pragma unroll 8
    for(int kg=0; kg<32; kg++){
      float4 a  = ab[kg*256];
      float4 h0 = h1l4[0][h*32+kg];
      float4 h1 = h1l4[1][h*32+kg];
      float4 h2v= h1l4[2][h*32+kg];
      float4 h3 = h1l4[3][h*32+kg];
      r0 += a.x*h0.x + a.y*h0.y + a.z*h0.z + a.w*h0.w;
      r1 += a.x*h1.x + a.y*h1.y + a.z*h1.z + a.w*h1.w;
      r2 += a.x*h2v.x + a.y*h2v.y + a.z*h2v.z + a.w*h2v.w;
      r3 += a.x*h3.x + a.y*h3.y + a.z*h3.z + a.w*h3.w;
    }
    ps[0+h][j] = r0; ps[2+h][j] = r1; ps[4+h][j] = r2; ps[6+h][j] = r3;
  }
  __syncthreads();
  float rr0=0.f, rr1=0.f, rr2=0.f, rr3=0.f;
  if(tid < 256){
    rr0 = ps[0][tid]+ps[1][tid];
    rr1 = ps[2][tid]+ps[3][tid];
    rr2 = ps[4][tid]+ps[5][tid];
    rr3 = ps[6][tid]+ps[7][tid];
    h2[(b*GCH+c0+0)*SS + tid] = rr0;
    h2[(b*GCH+c0+1)*SS + tid] = rr1;
    h2[(b*GCH+c0+2)*SS + tid] = rr2;
    h2[(b*GCH+c0+3)*SS + tid] = rr3;
  }
  for(int off=32; off; off>>=1){
    rr0 += __shfl_down(rr0,off); rr1 += __shfl_down(rr1,off);
    rr2 += __shfl_down(rr2,off); rr3 += __shfl_down(rr3,off);
  }
  if(tid < 256 && (tid & 63)==0){
    int w3 = tid >> 6;
    red[0][w3]=rr0; red[1][w3]=rr1; red[2][w3]=rr2; red[3][w3]=rr3;
  }
  __syncthreads();
  if(tid < 4)
    m[b*GCH + c0 + tid] =
      (red[tid][0]+red[tid][1]+red[tid][2]+red[tid][3])*(1.f/256.f);
}

// ---- fused style L1 + L2 + AdaIN apply: 32 blocks x 512 threads ----
__global__ __launch_bounds__(512) void k_s12(const float* __restrict__ m,
        const float* __restrict__ a1w, const float* __restrict__ a1b,
        const float* __restrict__ a2w, const float* __restrict__ a2b,
        const float* __restrict__ h2, float sc1, float sc2,
        float4* __restrict__ xp2){
  int q = blockIdx.x;               // 0..31
  int tid = threadIdx.x;
  int lane = tid & 63, wv = tid >> 6;      // wv 0..7
  int grp = lane >> 3, ll = lane & 7;
  __shared__ float4 ml4[256];       // m: [b*64 + i]
  __shared__ float s1l[4][512];     // s1 stored at [(row&7)*64 + (row>>3)]
  __shared__ float gbl[4][16];
  if(tid < 256) ml4[tid] = ((const float4*)m)[tid];
  __syncthreads();
  #pragma unroll 2
  for(int pass=0; pass<8; pass++){
    int row = wv*64 + pass*8 + grp;
    const float4* ar = (const float4*)(a1w + row*GCH) + ll;
    float p0=0.f,p1=0.f,p2=0.f,p3=0.f;
    #pragma unroll
    for(int j=0;j<8;j++){
      float4 w4 = ar[j*8];
      float4 m0 = ml4[0*64 + j*8 + ll];
      float4 m1 = ml4[1*64 + j*8 + ll];
      float4 m2 = ml4[2*64 + j*8 + ll];
      float4 m3 = ml4[3*64 + j*8 + ll];
      p0 += w4.x*m0.x + w4.y*m0.y + w4.z*m0.z + w4.w*m0.w;
      p1 += w4.x*m1.x + w4.y*m1.y + w4.z*m1.z + w4.w*m1.w;
      p2 += w4.x*m2.x + w4.y*m2.y + w4.z*m2.z + w4.w*m2.w;
      p3 += w4.x*m3.x + w4.y*m3.y + w4.z*m3.z + w4.w*m3.w;
    }
    #pragma unroll
    for(int off=1; off<8; off<<=1){
      p0 += __shfl_xor(p0,off); p1 += __shfl_xor(p1,off);
      p2 += __shfl_xor(p2,off); p3 += __shfl_xor(p3,off);
    }
    if(ll == 0){
      float bv = a1b[row];
      int sidx = ((row & 7) << 6) + (row >> 3);
      s1l[0][sidx] = lrelu(p0*sc1 + bv);
      s1l[1][sidx] = lrelu(p1*sc1 + bv);
      s1l[2][sidx] = lrelu(p2*sc1 + bv);
      s1l[3][sidx] = lrelu(p3*sc1 + bv);
    }
  }
  __syncthreads();
  float sA[4][8];
  #pragma unroll
  for(int b=0;b<4;b++)
    #pragma unroll
    for(int j=0;j<8;j++) sA[b][j] = s1l[b][j*64 + lane];
  #pragma unroll
  for(int r=0;r<2;r++){
    int ridx = wv*2 + r;            // 0..15
    int cc = ridx & 7;
    int t = (ridx < 8) ? (q*8 + cc) : (256 + q*8 + cc);
    const float* wr = a2w + t*512 + lane*8;
    float4 wa = *(const float4*)wr;
    float4 wb4 = *(const float4*)(wr+4);
    float p0 = wa.x*sA[0][0]+wa.y*sA[0][1]+wa.z*sA[0][2]+wa.w*sA[0][3]
             + wb4.x*sA[0][4]+wb4.y*sA[0][5]+wb4.z*sA[0][6]+wb4.w*sA[0][7];
    float p1 = wa.x*sA[1][0]+wa.y*sA[1][1]+wa.z*sA[1][2]+wa.w*sA[1][3]
             + wb4.x*sA[1][4]+wb4.y*sA[1][5]+wb4.z*sA[1][6]+wb4.w*sA[1][7];
    float p2 = wa.x*sA[2][0]+wa.y*sA[2][1]+wa.z*sA[2][2]+wa.w*sA[2][3]
             + wb4.x*sA[2][4]+wb4.y*sA[2][5]+wb4.z*sA[2][6]+wb4.w*sA[2][7];
    float p3 = wa.x*sA[3][0]+wa.y*sA[3][1]+wa.z*sA[3][2]+wa.w*sA[3][3]
             + wb4.x*sA[3][4]+wb4.y*sA[3][5]+wb4.z*sA[3][6]+wb4.w*sA[3][7];
    for(int off=32; off; off>>=1){
      p0 += __shfl_xor(p0,off); p1 += __shfl_xor(p1,off);
      p2 += __shfl_xor(p2,off); p3 += __shfl_xor(p3,off);
    }
    if(lane < 4){
      float p = lane==0 ? p0 : lane==1 ? p1 : lane==2 ? p2 : p3;
      gbl[lane][ridx] = p*sc2 + a2b[t];
    }
  }
  __syncthreads();
  int j = tid & 255;
  int cg2 = tid >> 8;               // 0..1
  int cbase = q*8 + cg2*4;
  int cg = cbase >> 2;
  #pragma unroll
  for(int b=0;b<4;b++){
    float4 o;
    o.x = lrelu(gbl[b][cg2*4+0]*h2[(b*GCH + cbase+0)*SS + j] + gbl[b][8+cg2*4+0]);
    o.y = lrelu(gbl[b][cg2*4+1]*h2[(b*GCH + cbase+1)*SS + j] + gbl[b][8+cg2*4+1]);
    o.z = lrelu(gbl[b][cg2*4+2]*h2[(b*GCH + cbase+2)*SS + j] + gbl[b][8+cg2*4+2]);
    o.w = lrelu(gbl[b][cg2*4+3]*h2[(b*GCH + cbase+3)*SS + j] + gbl[b][8+cg2*4+3]);
    xp2[(b*64 + cg)*256 + j] = o;
  }
}

// ---- v[b][k][s][o] = sum_c wT[k][c][o] * xp[c][s], wT staged in LDS ----
__global__ __launch_bounds__(256) void k_v(const float4* __restrict__ xp2,
        const float4* __restrict__ wT4, float4* __restrict__ v4){
  int s0 = blockIdx.x*16;           // grid (16,9,4)
  int k  = blockIdx.y;
  int b  = blockIdx.z;
  int tid = threadIdx.x;
  __shared__ float4 wl[64][33];
  __shared__ float xft[256][17];
  for(int t = tid; t < 1024; t += 256){
    int cg = t >> 4, si = t & 15;
    float4 xv = xp2[(b*64 + cg)*256 + s0 + si];
    xft[cg*4+0][si] = xv.x;
    xft[cg*4+1][si] = xv.y;
    xft[cg*4+2][si] = xv.z;
    xft[cg*4+3][si] = xv.w;
  }
  int og = tid & 31, sh = tid >> 5;  // sh 0..7
  const float4* wb = wT4 + (size_t)k*GCH*32;
  float4 a0 = {0.f,0.f,0.f,0.f}, a1 = {0.f,0.f,0.f,0.f};
  for(int ct=0; ct<4; ct++){
    __syncthreads();
    for(int t = tid; t < 2048; t += 256){
      int cc = t>>5, o = t&31;
      wl[cc][o] = wb[(ct*64+cc)*32 + o];
    }
    __syncthreads();
    #pragma unroll 4
    for(int cc=0;cc<64;cc++){
      float4 w = wl[cc][og];
      int c = ct*64+cc;
      float x0v = xft[c][sh];
      float x1v = xft[c][8+sh];
      a0.x += w.x*x0v; a0.y += w.y*x0v; a0.z += w.z*x0v; a0.w += w.w*x0v;
      a1.x += w.x*x1v; a1.y += w.y*x1v; a1.z += w.z*x1v; a1.w += w.w*x1v;
    }
  }
  size_t base = (size_t)(b*9+k)*SS + s0;
  v4[(base + sh)*32 + og]     = a0;
  v4[(base + 8 + sh)*32 + og] = a1;
}

// ---- fused conv1-gather(paired float4) + conv2 (scalar weights), 8x8 tile ----
__global__ __launch_bounds__(256) void k_conv(const float4* __restrict__ v4,
        const int* __restrict__ seg, const float4* __restrict__ b14,
        const float* __restrict__ w2t, float* __restrict__ y2){
  __shared__ float4 y1t4[100*9];    // [pp][8 ch-f4 + pad]
  __shared__ int   segl[144];
  __shared__ float part[768];
  int bid = blockIdx.x;
  int x = bid & 7;
  int b = x >> 1;
  int sub = ((bid >> 3) << 1) + (x & 1);  // 0..4095
  int g = sub & 3;
  int tile = sub >> 2;
  int x0p = (tile & 31)*8, y0p = (tile >> 5)*8;
  int tid = threadIdx.x;
  if(tid < 144){
    int r = tid/12, cc = tid%12;
    int gy = y0p - 2 + r, gx = x0p - 2 + cc;
    segl[tid] = (gy>=0 && gy<256 && gx>=0 && gx<256) ? seg[(b*256+gy)*256+gx] : -1;
  }
  __syncthreads();
  int o2 = tid & 3;                 // pair index: channels-f4 {o2*2, o2*2+1}
  const float4* vb = v4 + (size_t)(b*9)*SS*32 + g*8 + o2*2;
  float4 biasA = b14[g*8 + o2*2];
  float4 biasB = b14[g*8 + o2*2 + 1];
  bool interior = (x0p >= 8 && x0p <= 240 && y0p >= 8 && y0p <= 240);
  if(interior){
    for(int task = tid; task < 400; task += 256){
      int pp = task >> 2;
      int py = pp/10, px = pp - py*10;
      float4 aA = biasA, aB = biasB;
      #pragma unroll
      for(int k=0;k<9;k++){
        int sidx = segl[(py + k/3)*12 + (px + k%3)];
        const float4* pv = vb + (k*SS + sidx)*32;
        float4 vA = pv[0], vB = pv[1];
        aA.x += vA.x; aA.y += vA.y; aA.z += vA.z; aA.w += vA.w;
        aB.x += vB.x; aB.y += vB.y; aB.z += vB.z; aB.w += vB.w;
      }
      float4 valA, valB;
      valA.x = lrelu(aA.x); valA.y = lrelu(aA.y); valA.z = lrelu(aA.z); valA.w = lrelu(aA.w);
      valB.x = lrelu(aB.x); valB.y = lrelu(aB.y); valB.z = lrelu(aB.z); valB.w = lrelu(aB.w);
      y1t4[pp*9 + o2*2]     = valA;
      y1t4[pp*9 + o2*2 + 1] = valB;
    }
  } else {
    for(int task = tid; task < 400; task += 256){
      int pp = task >> 2;
      int py = pp/10, px = pp - py*10;
      int gy = y0p - 1 + py, gx = x0p - 1 + px;
      bool pix_ok = (gy>=0 && gy<256 && gx>=0 && gx<256);
      float4 aA = biasA, aB = biasB;
      #pragma unroll
      for(int k=0;k<9;k++){
        int sidx = segl[(py + k/3)*12 + (px + k%3)];
        int sidx0 = sidx < 0 ? 0 : sidx;
        float msk = sidx < 0 ? 0.f : 1.f;
        const float4* pv = vb + (k*SS + sidx0)*32;
        float4 vA = pv[0], vB = pv[1];
        aA.x += msk*vA.x; aA.y += msk*vA.y; aA.z += msk*vA.z; aA.w += msk*vA.w;
        aB.x += msk*vB.x; aB.y += msk*vB.y; aB.z += msk*vB.z; aB.w += msk*vB.w;
      }
      float4 valA, valB;
      valA.x = pix_ok ? lrelu(aA.x) : 0.f;
      valA.y = pix_ok ? lrelu(aA.y) : 0.f;
      valA.z = pix_ok ? lrelu(aA.z) : 0.f;
      valA.w = pix_ok ? lrelu(aA.w) : 0.f;
      valB.x = pix_ok ? lrelu(aB.x) : 0.f;
      valB.y = pix_ok ? lrelu(aB.y) : 0.f;
      valB.z = pix_ok ? lrelu(aB.z) : 0.f;
      valB.w = pix_ok ? lrelu(aB.w) : 0.f;
      y1t4[pp*9 + o2*2]     = valA;
      y1t4[pp*9 + o2*2 + 1] = valB;
    }
  }
  __syncthreads();
  int pxo = tid & 63, sg = tid >> 6;
  int sgu = __builtin_amdgcn_readfirstlane(sg);
  const float* wk0 = w2t + (g*4 + sgu)*24;   // + k*384
  int ty = pxo >> 3, tx = pxo & 7;
  float p0=0.f,p1=0.f,p2=0.f;
  #pragma unroll
  for(int k=0;k<9;k++){
    int pp0 = (ty + k/3)*10 + (tx + k%3);
    float4 ya = y1t4[pp0*9 + sgu*2];
    float4 yb = y1t4[pp0*9 + sgu*2 + 1];
    const float* wk = wk0 + k*384;
    p0 += wk[0]*ya.x + wk[1]*ya.y + wk[2]*ya.z + wk[3]*ya.w
        + wk[4]*yb.x + wk[5]*yb.y + wk[6]*yb.z + wk[7]*yb.w;
    p1 += wk[8]*ya.x + wk[9]*ya.y + wk[10]*ya.z + wk[11]*ya.w
        + wk[12]*yb.x + wk[13]*yb.y + wk[14]*yb.z + wk[15]*yb.w;
    p2 += wk[16]*ya.x + wk[17]*ya.y + wk[18]*ya.z + wk[19]*ya.w
        + wk[20]*yb.x + wk[21]*yb.y + wk[22]*yb.z + wk[23]*yb.w;
  }
  part[tid]     = p0;
  part[256+tid] = p1;
  part[512+tid] = p2;
  __syncthreads();
  if(tid < 64){
    float s0 = part[tid]    +part[tid+64]    +part[tid+128]    +part[tid+192];
    float s1 = part[256+tid]+part[256+tid+64]+part[256+tid+128]+part[256+tid+192];
    float s2 = part[512+tid]+part[512+tid+64]+part[512+tid+128]+part[512+tid+192];
    int gy = y0p + (tid>>3), gx = x0p + (tid&7);
    int nidx = gy*256+gx;
    atomicAdd(&y2[(b*3+0)*NPIX+nidx], s0);
    atomicAdd(&y2[(b*3+1)*NPIX+nidx], s1);
    atomicAdd(&y2[(b*3+2)*NPIX+nidx], s2);
  }
}

// ---- per (b,channel) sum & sumsq, parallel chunks with f64 atomics ----
__global__ void k_stats(const float* __restrict__ y2, double* __restrict__ stats){
  int bc = blockIdx.x;     // 12
  int chunk = blockIdx.y;  // 8
  const float* p = y2 + (size_t)bc*NPIX + chunk*8192;
  int t = threadIdx.x;
  double s=0.0, q=0.0;
  for(int i=t;i<8192;i+=256){ double vv = (double)p[i]; s+=vv; q+=vv*vv; }
  __shared__ double rs[256], rq[256];
  rs[t]=s; rq[t]=q; __syncthreads();
  for(int st=128; st; st>>=1){ if(t<st){rs[t]+=rs[t+st]; rq[t]+=rq[t+st];} __syncthreads(); }
  if(t==0){ atomicAdd(&stats[bc*2], rs[0]); atomicAdd(&stats[bc*2+1], rq[0]); }
}

// ---- instance norm + tanh ----
__global__ void k_norm(const float* __restrict__ y2, const double* __restrict__ stats,
                       float* __restrict__ out){
  int bu = (blockIdx.x*256) >> 16;           // uniform per block
  double mu  = stats[bu*2+0] * (1.0/65536.0);
  double ex2 = stats[bu*2+1] * (1.0/65536.0);
  double var = ex2 - mu*mu;
  float inv = (float)(1.0/sqrt(var + 1e-5));
  float mf = (float)mu;
  int idx = blockIdx.x*256+threadIdx.x;
  out[idx] = tanhf((y2[idx]-mf)*inv);
}

extern "C" void kernel_launch(void* const* d_in, const int* in_sizes, int n_in,
                              void* d_out, int out_size, void* d_ws, size_t ws_size,
                              hipStream_t stream) {
  const float* z   = (const float*)d_in[0];
  const float* img = (const float*)d_in[1];
  const int*   seg = (const int*)d_in[2];
  const float* A   = (const float*)d_in[3];
  const float* pw  = (const float*)d_in[4];
  const float* pb  = (const float*)d_in[5];
  const float* bw  = (const float*)d_in[6];
  const float* bb  = (const float*)d_in[7];
  const float* a1w = (const float*)d_in[8];
  const float* a1b = (const float*)d_in[9];
  const float* a2w = (const float*)d_in[10];
  const float* a2b = (const float*)d_in[11];
  const float* w1  = (const float*)d_in[12];
  const float* b1  = (const float*)d_in[13];
  const float* w2  = (const float*)d_in[14];
  const float* b2  = (const float*)d_in[15]; (void)b2; // cancels under InstanceNorm
  float* out = (float*)d_out;

  float* ws = (float*)d_ws;
  float* segsum = ws;                    // 3072
  float* counts = ws + 3072;             // 1024 -> 4096
  float* m      = ws + 4096;             // 1024 -> 5120
  double* stats = (double*)(ws + 5120);  // 24 doubles -> 5168, pad to 5248
  float* xp2 = ws + 5248;                // 262144 (16B-aligned)
  float* h2  = xp2 + 262144;             // 262144
  float* At2 = h2 + 262144;              // 262144
  float* wT  = At2 + 262144;             // 294912
  float* v   = wT + 294912;              // 1179648
  float* y2  = v + 1179648;              // 786432
  float* w2t = y2 + 786432;              // 3456   (end ~12.2 MB)

  hipMemsetAsync(ws, 0, 5248*sizeof(float), stream);     // sums + stats
  hipMemsetAsync(y2, 0, 786432*sizeof(float), stream);   // conv2 accumulator

  float sProj = (float)sqrt(2.0/131.0);
  float s256  = (float)sqrt(2.0/256.0);
  float s512  = (float)sqrt(2.0/512.0);

  k_pp  <<<512 + 1166, 256, 0, stream>>>(img, seg, segsum, counts,
                                         A, w1, w2, At2, wT, w2t);
  k_x0  <<<dim3(64,4), 256, 0, stream>>>(segsum, counts, z, pw, pb, sProj,
                                         (float4*)xp2);

  for(int blk=0; blk<NBLKS; blk++){
    k_gemm<<<dim3(64,4), 512, 0, stream>>>((const float4*)xp2,
                                           bw + blk*GCH*GCH, bb + blk*GCH,
                                           (const float4*)At2, s256, h2, m);
    k_s12 <<<32, 512, 0, stream>>>(m, a1w + blk*512*GCH, a1b + blk*512,
                                   a2w + blk*512*512, a2b + blk*512,
                                   h2, s256, s512, (float4*)xp2);
  }

  k_v   <<<dim3(16,9,4), 256, 0, stream>>>((const float4*)xp2, (const float4*)wT,
                                           (float4*)v);
  k_conv<<<16384, 256, 0, stream>>>((const float4*)v, seg, (const float4*)b1, w2t, y2);
  k_stats<<<dim3(12,8), 256, 0, stream>>>(y2, stats);
  k_norm<<<3072, 256, 0, stream>>>(y2, stats, out);
}